// Round 18
// baseline (76.307 us; speedup 1.0000x reference)
//
#include <hip/hip_runtime.h>
#include <hip/hip_bf16.h>
#include <stdint.h>

typedef float f32x4 __attribute__((ext_vector_type(4)));
typedef float f32x4v __attribute__((ext_vector_type(4)));
typedef short short8 __attribute__((ext_vector_type(8)));
typedef unsigned short u16;
typedef unsigned short u16x8 __attribute__((ext_vector_type(8)));
typedef unsigned short u16x4 __attribute__((ext_vector_type(4)));

#define MFMA16x16x32 __builtin_amdgcn_mfma_f32_16x16x32_bf16

__device__ __forceinline__ u16 f2bf(float f) {
    unsigned int u = __builtin_bit_cast(unsigned int, f);
    u += 0x7fffu + ((u >> 16) & 1u);
    return (u16)(u >> 16);
}
__device__ __forceinline__ float bf2f(u16 v) {
    unsigned int u = ((unsigned int)v) << 16;
    return __builtin_bit_cast(float, u);
}

__device__ __forceinline__ void gload_lds16(const void* g, void* l) {
    __builtin_amdgcn_global_load_lds(
        (const __attribute__((address_space(1))) uint32_t*)g,
        (__attribute__((address_space(3))) uint32_t*)l, 16, 0, 0);
}

// z-blocks for the small qt2 of pair p: na = 2p+2 tiles of the pair's 34.
__device__ __forceinline__ int z_small2(int na) {
    int za = (8 * na + 33) / 34;
    za = za < 1 ? 1 : za;
    return za > 7 ? 7 : za;
}

// ---------------------------------------------------------------------------
// Kernel 0: W [1024,128] f32 -> WTf, MFMA-FRAGMENT-ORDERED bf16.
// Fragment f = (kt*2+ks)*24 + nc; chunk (f,lane) = 16B at WTf + f*1024 + lane*16.
// ---------------------------------------------------------------------------
__global__ void k_transpose_wf(const float* __restrict__ Wq, const float* __restrict__ Wk,
                               const float* __restrict__ Wv, u16* __restrict__ WTf) {
    int tid  = blockIdx.x * 256 + threadIdx.x;   // 0..49151
    int f    = tid >> 6;                         // 0..767
    int lane = tid & 63;
    int kt  = f / 48;
    int rem = f % 48;
    int ks  = rem / 24;
    int nc  = rem % 24;
    int col = nc * 16 + (lane & 15);
    int w   = col >> 7, n = col & 127;
    int k0  = kt * 64 + ks * 32 + (lane >> 4) * 8;
    const float* W = (w == 0) ? Wq : ((w == 1) ? Wk : Wv);
    u16x8 v;
#pragma unroll
    for (int j = 0; j < 8; ++j)
        v[j] = f2bf(W[(size_t)(k0 + j) * 128 + n]);
    *(u16x8*)(&WTf[(size_t)tid * 8]) = v;
}

// ---------------------------------------------------------------------------
// Kernel 1: FUSED QKV GEMM — gemm8 (best-measured, unchanged).
// ---------------------------------------------------------------------------
__global__ __launch_bounds__(512) void k_qkv_gemm8(
    const float* __restrict__ x, const u16* __restrict__ WTf,
    u16* __restrict__ qb, u16* __restrict__ kb, u16* __restrict__ vT)
{
    __shared__ u16 abuf[2][64 * 64];     // 2 x 8 KB
    __shared__ u16 bbuf[2][384 * 64];    // 2 x 48 KB
    const int tid  = threadIdx.x;
    const int lane = tid & 63, wid = tid >> 6;
    const int wr = wid >> 2, wc = wid & 3;
    const int lrow = lane & 15, lk = lane >> 4;
    const int m0 = blockIdx.x * 64;

    const int arow = tid >> 3;            // 0..63
    const int aseg = tid & 7;             // 0..7 (8 f32 each)
    const float* xsrc = x + (size_t)(m0 + arow) * 1024 + aseg * 8;

    f32x4 acc[2][6];
#pragma unroll
    for (int i = 0; i < 2; ++i)
#pragma unroll
        for (int j = 0; j < 6; ++j) acc[i][j] = (f32x4){0.f, 0.f, 0.f, 0.f};

#define LOADA(s0, s1, ktv)                                                     \
    s0 = *(const f32x4v*)(xsrc + (ktv) * 64);                                  \
    s1 = *(const f32x4v*)(xsrc + (ktv) * 64 + 4);

#define STOREA(buf, s0, s1)                                                    \
    {   u16x8 v;                                                               \
        v[0]=f2bf(s0[0]); v[1]=f2bf(s0[1]); v[2]=f2bf(s0[2]); v[3]=f2bf(s0[3]); \
        v[4]=f2bf(s1[0]); v[5]=f2bf(s1[1]); v[6]=f2bf(s1[2]); v[7]=f2bf(s1[3]); \
        *(u16x8*)(&buf[arow * 64 + ((aseg ^ (arow & 7)) << 3)]) = v; }

#define ISSUEB(buf, ktv)                                                       \
    {   const u16* bsrc = WTf + (size_t)(ktv) * 24576;                         \
        _Pragma("unroll") for (int i = 0; i < 6; ++i) {                        \
            int c = tid + i * 512;                                             \
            gload_lds16(bsrc + c * 8, &buf[c * 8]);                            \
        } }

#define COMPUTE(ab, bb)                                                        \
    _Pragma("unroll") for (int ks = 0; ks < 2; ++ks) {                         \
        short8 af[2];                                                          \
        _Pragma("unroll") for (int mf = 0; mf < 2; ++mf) {                     \
            int row = wr * 32 + mf * 16 + lrow;                                \
            int blk = (ks * 4 + lk) ^ (row & 7);                               \
            af[mf] = *(const short8*)(&ab[row * 64 + (blk << 3)]);             \
        }                                                                      \
        _Pragma("unroll") for (int nf = 0; nf < 6; ++nf) {                     \
            short8 bfr = *(const short8*)(&bb[(ks * 24 + wc * 6 + nf) * 512 + lane * 8]); \
            _Pragma("unroll") for (int mf = 0; mf < 2; ++mf)                   \
                acc[mf][nf] = MFMA16x16x32(af[mf], bfr, acc[mf][nf], 0, 0, 0); \
        } }

#define WAITBAR()                                                              \
    asm volatile("s_waitcnt vmcnt(2) lgkmcnt(0)\n\ts_barrier" ::: "memory");   \
    __builtin_amdgcn_sched_barrier(0);

    f32x4v a0A, a1A, a0B, a1B;
    LOADA(a0A, a1A, 0);
    LOADA(a0B, a1B, 1);
    STOREA(abuf[0], a0A, a1A);
    ISSUEB(bbuf[0], 0);
    LOADA(a0A, a1A, 2);
    WAITBAR();

    for (int kt = 0; kt < 16; kt += 2) {
        {
            const int ktn = (kt + 1 < 16) ? kt + 1 : 15;
            ISSUEB(bbuf[1], ktn);
            __builtin_amdgcn_sched_barrier(0);
            COMPUTE(abuf[0], bbuf[0]);
            STOREA(abuf[1], a0B, a1B);
            const int kp = (kt + 3 < 16) ? kt + 3 : 15;
            LOADA(a0B, a1B, kp);
            WAITBAR();
        }
        {
            const int ktn = (kt + 2 < 16) ? kt + 2 : 15;
            ISSUEB(bbuf[0], ktn);
            __builtin_amdgcn_sched_barrier(0);
            COMPUTE(abuf[1], bbuf[1]);
            STOREA(abuf[0], a0A, a1A);
            const int kp = (kt + 4 < 16) ? kt + 4 : 15;
            LOADA(a0A, a1A, kp);
            WAITBAR();
        }
    }
#undef LOADA
#undef STOREA
#undef ISSUEB
#undef COMPUTE
#undef WAITBAR

#pragma unroll
    for (int nf = 0; nf < 6; ++nf) {
        const int gc   = wc * 96 + nf * 16 + lrow;
        const int wsel = gc >> 7;
        const int col  = gc & 127;
#pragma unroll
        for (int mf = 0; mf < 2; ++mf) {
            const int row0 = m0 + wr * 32 + mf * 16 + lk * 4;
            if (wsel == 0) {
#pragma unroll
                for (int jj = 0; jj < 4; ++jj)
                    qb[(size_t)(row0 + jj) * 128 + col] = f2bf(acc[mf][nf][jj]);
            } else if (wsel == 1) {
#pragma unroll
                for (int jj = 0; jj < 4; ++jj)
                    kb[(size_t)(row0 + jj) * 128 + col] = f2bf(acc[mf][nf][jj]);
            } else {
                const int bb = row0 >> 11, t0 = row0 & 2047;
                u16x4 v;
#pragma unroll
                for (int jj = 0; jj < 4; ++jj) v[jj] = f2bf(acc[mf][nf][jj]);
                *(u16x4*)(&vT[((size_t)bb * 128 + col) * 2048 + t0]) = v;
            }
        }
    }
}

// ---------------------------------------------------------------------------
// Kernel 2 (v9): causal flash, BQ=128 / 8 waves — K/V staged ONCE per tile
// for 2x the q-rows (halves L2->LDS DMA traffic, the measured dominant cost).
// Grid 512 = 8 b x 8 pairs x 8 z.  Pair (p, 15-p): 34 tiles; aligned z-split
// (za blocks for small qt2), every block <=5 tiles.  Double-buffered K/V with
// full-tile-early prefetch, one vmcnt(0) barrier per tile (count-free).
// Fully-masked waves produce finite garbage with m=-1e30 -> weight 0 in
// combine (annihilated).  LDS 80KB -> 2 blocks/CU, 16 waves/CU.
// ---------------------------------------------------------------------------
__global__ __launch_bounds__(512) void k_flash8(
    const u16* __restrict__ qb, const u16* __restrict__ kb, const u16* __restrict__ vT,
    u16* __restrict__ po, float* __restrict__ pm, float* __restrict__ pl)
{
    __shared__ u16 k_lds[2][64 * 128];   // 2 x 16 KB
    __shared__ u16 v_lds[2][128 * 64];   // 2 x 16 KB
    __shared__ u16 p_lds[8 * 16 * 64];   // 16 KB
    const int tid  = threadIdx.x;
    const int lane = tid & 63, wid = tid >> 6;     // wid 0..7
    const int lrow = lane & 15, lk = lane >> 4;
    const int bx = blockIdx.x;
    const int b  = bx & 7;
    const int pu = (bx >> 3) & 7;
    const int z  = bx >> 6;

    const int na = 2 * pu + 2;
    const int za = z_small2(na);
    int qt2, n2, k, Z;
    if (z < za) { qt2 = pu;      n2 = na;          k = z;      Z = za;     }
    else        { qt2 = 15 - pu; n2 = 32 - 2 * pu; k = z - za; Z = 8 - za; }
    const int t0 = (k * n2) / Z;
    const int t1 = ((k + 1) * n2) / Z;

    const int qbase = qt2 * 128 + wid * 16;        // this wave's 16 q-rows
    short8 qf[4];
    {
        const u16* qp = qb + ((size_t)b * 2048 + qbase + lrow) * 128;
#pragma unroll
        for (int ks = 0; ks < 4; ++ks) qf[ks] = *(const short8*)(qp + ks * 32 + lk * 8);
    }
    f32x4 of[8];
#pragma unroll
    for (int i = 0; i < 8; ++i) of[i] = (f32x4){0.f, 0.f, 0.f, 0.f};
    float mrun[4], lsum[4];
#pragma unroll
    for (int j = 0; j < 4; ++j) { mrun[j] = -1e30f; lsum[j] = 0.f; }

    const u16* kbase = kb + (size_t)b * 2048 * 128;
    const u16* vbase = vT + (size_t)b * 128 * 2048;
    u16* pw = p_lds + wid * (16 * 64);

#define ISSUE_KV(c_, t_)                                                       \
    {   const int kv0_ = (t_) << 6;                                            \
        _Pragma("unroll") for (int i = 0; i < 2; ++i) {                        \
            int ch = tid + i * 512;                                            \
            int row = ch >> 4, blk = ch & 15;                                  \
            gload_lds16(kbase + (size_t)(kv0_ + row) * 128 + ((blk ^ (row & 7)) << 3), \
                        &k_lds[c_][ch * 8]);                                   \
        }                                                                      \
        _Pragma("unroll") for (int i = 0; i < 2; ++i) {                        \
            int ch = tid + i * 512;                                            \
            int row = ch >> 3, blk = ch & 7;                                   \
            gload_lds16(vbase + (size_t)row * 2048 + kv0_ + ((blk ^ (row & 7)) << 3), \
                        &v_lds[c_][ch * 8]);                                   \
        }                                                                      \
        __builtin_amdgcn_sched_barrier(0); }

    ISSUE_KV(0, t0);                      // prologue prefetch
    int c = 0;

    for (int t = t0; t < t1; ++t) {
        const int kv0 = t << 6;
        asm volatile("s_waitcnt vmcnt(0) lgkmcnt(0)\n\ts_barrier" ::: "memory");
        __builtin_amdgcn_sched_barrier(0);
        if (t + 1 < t1) ISSUE_KV(c ^ 1, t + 1);   // overlaps this tile's compute

        f32x4 sf[4];
#pragma unroll
        for (int nf = 0; nf < 4; ++nf) sf[nf] = (f32x4){0.f, 0.f, 0.f, 0.f};
#pragma unroll
        for (int ks = 0; ks < 4; ++ks)
#pragma unroll
            for (int nf = 0; nf < 4; ++nf) {
                int row = nf * 16 + lrow;
                int blk = (ks * 4 + lk) ^ (row & 7);
                short8 bfr = *(const short8*)(&k_lds[c][row * 128 + (blk << 3)]);
                sf[nf] = MFMA16x16x32(qf[ks], bfr, sf[nf], 0, 0, 0);
            }

        const bool needmask = (kv0 + 63 > qbase);  // per-wave causal edge
#pragma unroll
        for (int nf = 0; nf < 4; ++nf)
#pragma unroll
            for (int jj = 0; jj < 4; ++jj) {
                float s = sf[nf][jj] * 0.03125f;   // C^-0.5 = 1/32
                if (needmask && (kv0 + nf * 16 + lrow > qbase + lk * 4 + jj)) s = -1e30f;
                sf[nf][jj] = s;
            }
        float mt[4];
#pragma unroll
        for (int jj = 0; jj < 4; ++jj)
            mt[jj] = fmaxf(fmaxf(sf[0][jj], sf[1][jj]), fmaxf(sf[2][jj], sf[3][jj]));
#pragma unroll
        for (int off = 1; off < 16; off <<= 1)
#pragma unroll
            for (int jj = 0; jj < 4; ++jj)
                mt[jj] = fmaxf(mt[jj], __shfl_xor(mt[jj], off));
        bool small = true;
#pragma unroll
        for (int jj = 0; jj < 4; ++jj) small = small && (mt[jj] <= mrun[jj] + 8.f);
        if (!__all(small)) {
#pragma unroll
            for (int jj = 0; jj < 4; ++jj) {
                float mnew = fmaxf(mrun[jj], mt[jj]);
                float sc   = __expf(mrun[jj] - mnew);
                mrun[jj]   = mnew;
                lsum[jj]  *= sc;
#pragma unroll
                for (int df = 0; df < 8; ++df) of[df][jj] *= sc;
            }
        }
        float rs[4] = {0.f, 0.f, 0.f, 0.f};
#pragma unroll
        for (int nf = 0; nf < 4; ++nf)
#pragma unroll
            for (int jj = 0; jj < 4; ++jj) {
                float e = __expf(sf[nf][jj] - mrun[jj]);
                sf[nf][jj] = e;
                rs[jj] += e;
            }
#pragma unroll
        for (int off = 1; off < 16; off <<= 1)
#pragma unroll
            for (int jj = 0; jj < 4; ++jj)
                rs[jj] += __shfl_xor(rs[jj], off);
#pragma unroll
        for (int jj = 0; jj < 4; ++jj) lsum[jj] += rs[jj];

#pragma unroll
        for (int nf = 0; nf < 4; ++nf)
#pragma unroll
            for (int jj = 0; jj < 4; ++jj) {
                int row = lk * 4 + jj;
                int col = nf * 16 + lrow;
                pw[row * 64 + (((col >> 3) ^ (row & 7)) << 3) + (col & 7)] = f2bf(sf[nf][jj]);
            }
        asm volatile("s_waitcnt lgkmcnt(0)" ::: "memory");
        __builtin_amdgcn_sched_barrier(0);
        short8 paf[2];
#pragma unroll
        for (int ks2 = 0; ks2 < 2; ++ks2) {
            int blk = (ks2 * 4 + lk) ^ (lrow & 7);
            paf[ks2] = *(const short8*)(&pw[lrow * 64 + (blk << 3)]);
        }
#pragma unroll
        for (int ks2 = 0; ks2 < 2; ++ks2)
#pragma unroll
            for (int df = 0; df < 8; ++df) {
                int row = df * 16 + lrow;
                int blk = (ks2 * 4 + lk) ^ (row & 7);
                short8 vf = *(const short8*)(&v_lds[c][row * 64 + (blk << 3)]);
                of[df] = MFMA16x16x32(paf[ks2], vf, of[df], 0, 0, 0);
            }
        c ^= 1;
    }
#undef ISSUE_KV

    u16* poslab = po + (size_t)bx * (128 * 128);
#pragma unroll
    for (int df = 0; df < 8; ++df)
#pragma unroll
        for (int jj = 0; jj < 4; ++jj)
            poslab[(size_t)(wid * 16 + lk * 4 + jj) * 128 + df * 16 + lrow] = f2bf(of[df][jj]);
    if (lrow == 0) {
#pragma unroll
        for (int jj = 0; jj < 4; ++jj) {
            pm[(size_t)bx * 128 + wid * 16 + lk * 4 + jj] = mrun[jj];
            pl[(size_t)bx * 128 + wid * 16 + lk * 4 + jj] = lsum[jj];
        }
    }
}

// ---------------------------------------------------------------------------
// Kernel 3 (v4): combine z-partials per 128-row super-tile; po is bf16.
// ---------------------------------------------------------------------------
__global__ __launch_bounds__(256) void k_combine(
    const u16* __restrict__ po, const float* __restrict__ pm, const float* __restrict__ pl,
    float* __restrict__ out)
{
    const int row  = blockIdx.x * 4 + (threadIdx.x >> 6);
    const int lane = threadIdx.x & 63;
    const int b   = row >> 11;
    const int t   = row & 2047;
    const int qt2 = t >> 7;
    const int r   = t & 127;

    const int p2 = (qt2 < 8) ? qt2 : 15 - qt2;
    const int za = z_small2(2 * p2 + 2);
    const int zlo = (qt2 < 8) ? 0 : za;
    const int zhi = (qt2 < 8) ? za : 8;

    float M = -1e30f;
    for (int z = zlo; z < zhi; ++z)
        M = fmaxf(M, pm[(size_t)(b + 8 * p2 + 64 * z) * 128 + r]);
    float den = 0.f, a0 = 0.f, a1 = 0.f;
    for (int z = zlo; z < zhi; ++z) {
        const int bxp = b + 8 * p2 + 64 * z;
        const float w = __expf(pm[(size_t)bxp * 128 + r] - M);
        den += w * pl[(size_t)bxp * 128 + r];
        const u16* slab = po + ((size_t)bxp * 128 + r) * 128;
        a0 += w * bf2f(slab[lane]);
        a1 += w * bf2f(slab[lane + 64]);
    }
    const float inv = 1.f / den;
    out[(size_t)row * 128 + lane]      = a0 * inv;
    out[(size_t)row * 128 + lane + 64] = a1 * inv;
}

// ---------------------------------------------------------------------------
extern "C" void kernel_launch(void* const* d_in, const int* in_sizes, int n_in,
                              void* d_out, int out_size, void* d_ws, size_t ws_size,
                              hipStream_t stream) {
    const float* x  = (const float*)d_in[0];
    const float* Wq = (const float*)d_in[1];
    const float* Wk = (const float*)d_in[2];
    const float* Wv = (const float*)d_in[3];
    float* out = (float*)d_out;

    char* ws = (char*)d_ws;
    u16*   qb  = (u16*)(ws);                         //  4 MB  [16384][128] bf16
    u16*   kb  = (u16*)(ws + (size_t)4  * 1048576);  //  4 MB  [16384][128] bf16
    u16*   vT  = (u16*)(ws + (size_t)8  * 1048576);  //  4 MB  [8][128][2048] bf16
    u16*   WTf = (u16*)(ws + (size_t)12 * 1048576);  //  0.75 MB fragment-ordered
    u16*   po  = (u16*)(ws + (size_t)13 * 1048576);  // 16.8 MB [512][128][128] bf16
    float* pm  = (float*)(ws + (size_t)47 * 1048576);//  0.25 MB [512][128]
    float* pl  = (float*)(ws + (size_t)48 * 1048576);//  0.25 MB [512][128]

    k_transpose_wf<<<192, 256, 0, stream>>>(Wq, Wk, Wv, WTf);
    k_qkv_gemm8<<<256, 512, 0, stream>>>(x, WTf, qb, kb, vT);
    k_flash8<<<512, 512, 0, stream>>>(qb, kb, vT, po, pm, pl);
    k_combine<<<4096, 256, 0, stream>>>(po, pm, pl, out);
}

// Round 19
// 74.677 us; speedup vs baseline: 1.0218x; 1.0218x over previous
//
#include <hip/hip_runtime.h>
#include <hip/hip_bf16.h>
#include <stdint.h>

typedef float f32x4 __attribute__((ext_vector_type(4)));
typedef float f32x4v __attribute__((ext_vector_type(4)));
typedef short short8 __attribute__((ext_vector_type(8)));
typedef unsigned short u16;
typedef unsigned short u16x8 __attribute__((ext_vector_type(8)));
typedef unsigned short u16x4 __attribute__((ext_vector_type(4)));

#define MFMA16x16x32 __builtin_amdgcn_mfma_f32_16x16x32_bf16

__device__ __forceinline__ u16 f2bf(float f) {
    unsigned int u = __builtin_bit_cast(unsigned int, f);
    u += 0x7fffu + ((u >> 16) & 1u);
    return (u16)(u >> 16);
}
__device__ __forceinline__ float bf2f(u16 v) {
    unsigned int u = ((unsigned int)v) << 16;
    return __builtin_bit_cast(float, u);
}

__device__ __forceinline__ void gload_lds16(const void* g, void* l) {
    __builtin_amdgcn_global_load_lds(
        (const __attribute__((address_space(1))) uint32_t*)g,
        (__attribute__((address_space(3))) uint32_t*)l, 16, 0, 0);
}

// z-blocks for the small qt of pair p (na = (p+2)>>1 kv128-tiles of the 17)
__device__ __forceinline__ int z_small128(int p) {
    int na = (p + 2) >> 1;
    int za = (8 * na + 16) / 17;
    za = za < 1 ? 1 : za;
    return za > 7 ? 7 : za;
}

// ---------------------------------------------------------------------------
// Kernel 0: W [1024,128] f32 -> WTf, MFMA-FRAGMENT-ORDERED bf16.
// Fragment f = (kt*2+ks)*24 + nc; chunk (f,lane) = 16B at WTf + f*1024 + lane*16.
// ---------------------------------------------------------------------------
__global__ void k_transpose_wf(const float* __restrict__ Wq, const float* __restrict__ Wk,
                               const float* __restrict__ Wv, u16* __restrict__ WTf) {
    int tid  = blockIdx.x * 256 + threadIdx.x;   // 0..49151
    int f    = tid >> 6;                         // 0..767
    int lane = tid & 63;
    int kt  = f / 48;
    int rem = f % 48;
    int ks  = rem / 24;
    int nc  = rem % 24;
    int col = nc * 16 + (lane & 15);
    int w   = col >> 7, n = col & 127;
    int k0  = kt * 64 + ks * 32 + (lane >> 4) * 8;
    const float* W = (w == 0) ? Wq : ((w == 1) ? Wk : Wv);
    u16x8 v;
#pragma unroll
    for (int j = 0; j < 8; ++j)
        v[j] = f2bf(W[(size_t)(k0 + j) * 128 + n]);
    *(u16x8*)(&WTf[(size_t)tid * 8]) = v;
}

// ---------------------------------------------------------------------------
// Kernel 1: FUSED QKV GEMM — gemm8 (best-measured, unchanged).
// ---------------------------------------------------------------------------
__global__ __launch_bounds__(512) void k_qkv_gemm8(
    const float* __restrict__ x, const u16* __restrict__ WTf,
    u16* __restrict__ qb, u16* __restrict__ kb, u16* __restrict__ vT)
{
    __shared__ u16 abuf[2][64 * 64];     // 2 x 8 KB
    __shared__ u16 bbuf[2][384 * 64];    // 2 x 48 KB
    const int tid  = threadIdx.x;
    const int lane = tid & 63, wid = tid >> 6;
    const int wr = wid >> 2, wc = wid & 3;
    const int lrow = lane & 15, lk = lane >> 4;
    const int m0 = blockIdx.x * 64;

    const int arow = tid >> 3;            // 0..63
    const int aseg = tid & 7;             // 0..7 (8 f32 each)
    const float* xsrc = x + (size_t)(m0 + arow) * 1024 + aseg * 8;

    f32x4 acc[2][6];
#pragma unroll
    for (int i = 0; i < 2; ++i)
#pragma unroll
        for (int j = 0; j < 6; ++j) acc[i][j] = (f32x4){0.f, 0.f, 0.f, 0.f};

#define LOADA(s0, s1, ktv)                                                     \
    s0 = *(const f32x4v*)(xsrc + (ktv) * 64);                                  \
    s1 = *(const f32x4v*)(xsrc + (ktv) * 64 + 4);

#define STOREA(buf, s0, s1)                                                    \
    {   u16x8 v;                                                               \
        v[0]=f2bf(s0[0]); v[1]=f2bf(s0[1]); v[2]=f2bf(s0[2]); v[3]=f2bf(s0[3]); \
        v[4]=f2bf(s1[0]); v[5]=f2bf(s1[1]); v[6]=f2bf(s1[2]); v[7]=f2bf(s1[3]); \
        *(u16x8*)(&buf[arow * 64 + ((aseg ^ (arow & 7)) << 3)]) = v; }

#define ISSUEB(buf, ktv)                                                       \
    {   const u16* bsrc = WTf + (size_t)(ktv) * 24576;                         \
        _Pragma("unroll") for (int i = 0; i < 6; ++i) {                        \
            int c = tid + i * 512;                                             \
            gload_lds16(bsrc + c * 8, &buf[c * 8]);                            \
        } }

#define COMPUTE(ab, bb)                                                        \
    _Pragma("unroll") for (int ks = 0; ks < 2; ++ks) {                         \
        short8 af[2];                                                          \
        _Pragma("unroll") for (int mf = 0; mf < 2; ++mf) {                     \
            int row = wr * 32 + mf * 16 + lrow;                                \
            int blk = (ks * 4 + lk) ^ (row & 7);                               \
            af[mf] = *(const short8*)(&ab[row * 64 + (blk << 3)]);             \
        }                                                                      \
        _Pragma("unroll") for (int nf = 0; nf < 6; ++nf) {                     \
            short8 bfr = *(const short8*)(&bb[(ks * 24 + wc * 6 + nf) * 512 + lane * 8]); \
            _Pragma("unroll") for (int mf = 0; mf < 2; ++mf)                   \
                acc[mf][nf] = MFMA16x16x32(af[mf], bfr, acc[mf][nf], 0, 0, 0); \
        } }

#define WAITBAR()                                                              \
    asm volatile("s_waitcnt vmcnt(2) lgkmcnt(0)\n\ts_barrier" ::: "memory");   \
    __builtin_amdgcn_sched_barrier(0);

    f32x4v a0A, a1A, a0B, a1B;
    LOADA(a0A, a1A, 0);
    LOADA(a0B, a1B, 1);
    STOREA(abuf[0], a0A, a1A);
    ISSUEB(bbuf[0], 0);
    LOADA(a0A, a1A, 2);
    WAITBAR();

    for (int kt = 0; kt < 16; kt += 2) {
        {
            const int ktn = (kt + 1 < 16) ? kt + 1 : 15;
            ISSUEB(bbuf[1], ktn);
            __builtin_amdgcn_sched_barrier(0);
            COMPUTE(abuf[0], bbuf[0]);
            STOREA(abuf[1], a0B, a1B);
            const int kp = (kt + 3 < 16) ? kt + 3 : 15;
            LOADA(a0B, a1B, kp);
            WAITBAR();
        }
        {
            const int ktn = (kt + 2 < 16) ? kt + 2 : 15;
            ISSUEB(bbuf[0], ktn);
            __builtin_amdgcn_sched_barrier(0);
            COMPUTE(abuf[1], bbuf[1]);
            STOREA(abuf[0], a0A, a1A);
            const int kp = (kt + 4 < 16) ? kt + 4 : 15;
            LOADA(a0A, a1A, kp);
            WAITBAR();
        }
    }
#undef LOADA
#undef STOREA
#undef ISSUEB
#undef COMPUTE
#undef WAITBAR

#pragma unroll
    for (int nf = 0; nf < 6; ++nf) {
        const int gc   = wc * 96 + nf * 16 + lrow;
        const int wsel = gc >> 7;
        const int col  = gc & 127;
#pragma unroll
        for (int mf = 0; mf < 2; ++mf) {
            const int row0 = m0 + wr * 32 + mf * 16 + lk * 4;
            if (wsel == 0) {
#pragma unroll
                for (int jj = 0; jj < 4; ++jj)
                    qb[(size_t)(row0 + jj) * 128 + col] = f2bf(acc[mf][nf][jj]);
            } else if (wsel == 1) {
#pragma unroll
                for (int jj = 0; jj < 4; ++jj)
                    kb[(size_t)(row0 + jj) * 128 + col] = f2bf(acc[mf][nf][jj]);
            } else {
                const int bb = row0 >> 11, t0 = row0 & 2047;
                u16x4 v;
#pragma unroll
                for (int jj = 0; jj < 4; ++jj) v[jj] = f2bf(acc[mf][nf][jj]);
                *(u16x4*)(&vT[((size_t)bb * 128 + col) * 2048 + t0]) = v;
            }
        }
    }
}

// ---------------------------------------------------------------------------
// Kernel 2 (v10): causal flash, KVBLK=128 — HALF the tile-load events
// (the measured invariant cost driver).  BQ=64, 4 waves; 17 kv128-tiles per
// qt-pair (p, 31-p) exactly; 8 z-blocks/pair, aligned split, 1..3 tiles each,
// no empty blocks.  Single-buffered K/V (flash6-style __syncthreads, proven).
// LDS: K 32K + V 32K + P 16K = 80KB -> 2 blocks/CU.
// ---------------------------------------------------------------------------
__global__ __launch_bounds__(256) void k_flash9(
    const u16* __restrict__ qb, const u16* __restrict__ kb, const u16* __restrict__ vT,
    u16* __restrict__ po, float* __restrict__ pm, float* __restrict__ pl)
{
    __shared__ u16 k_lds[128 * 128];     // 32 KB  [kv][d]
    __shared__ u16 v_lds[128 * 128];     // 32 KB  [d][kv]
    __shared__ u16 p_lds[4 * 16 * 128];  // 16 KB  per-wave 16x128
    const int tid  = threadIdx.x;
    const int lane = tid & 63, wid = tid >> 6;
    const int lrow = lane & 15, lk = lane >> 4;
    const int bx = blockIdx.x;
    const int b  = bx & 7;
    const int p  = (bx >> 3) & 15;
    const int z  = bx >> 7;

    const int za = z_small128(p);
    int qt, n, k, Z;
    if (z < za) { qt = p;      n = (p + 2) >> 1;  k = z;      Z = za;     }
    else        { qt = 31 - p; n = (33 - p) >> 1; k = z - za; Z = 8 - za; }
    const int t0 = (k * n) / Z;
    const int t1 = ((k + 1) * n) / Z;

    const int qrow0 = qt * 64;
    short8 qf[4];
    {
        const u16* qp = qb + ((size_t)b * 2048 + qrow0 + wid * 16 + lrow) * 128;
#pragma unroll
        for (int ks = 0; ks < 4; ++ks) qf[ks] = *(const short8*)(qp + ks * 32 + lk * 8);
    }
    f32x4 of[8];
#pragma unroll
    for (int i = 0; i < 8; ++i) of[i] = (f32x4){0.f, 0.f, 0.f, 0.f};
    float mrun[4], lsum[4];
#pragma unroll
    for (int j = 0; j < 4; ++j) { mrun[j] = -1e30f; lsum[j] = 0.f; }

    const u16* kbase = kb + (size_t)b * 2048 * 128;
    const u16* vbase = vT + (size_t)b * 128 * 2048;
    u16* pw = p_lds + wid * (16 * 128);

    for (int t = t0; t < t1; ++t) {
        const int kv0 = t << 7;
        __syncthreads();                  // readers of previous tile done
        // K tile: 2048 16B chunks, linear dest, pre-swizzled per-lane src
#pragma unroll
        for (int i = 0; i < 8; ++i) {
            int ch = tid + i * 256;
            int row = ch >> 4, blk = ch & 15;
            gload_lds16(kbase + (size_t)(kv0 + row) * 128 + ((blk ^ (row & 7)) << 3),
                        &k_lds[ch * 8]);
        }
        // V^T tile: 2048 chunks
#pragma unroll
        for (int i = 0; i < 8; ++i) {
            int ch = tid + i * 256;
            int row = ch >> 4, blk = ch & 15;
            gload_lds16(vbase + (size_t)row * 2048 + kv0 + ((blk ^ (row & 7)) << 3),
                        &v_lds[ch * 8]);
        }
        __syncthreads();                  // drains DMA (vmcnt0) + ds

        // ---- S = Q K^T : 8 n-frags ----
        f32x4 sf[8];
#pragma unroll
        for (int nf = 0; nf < 8; ++nf) sf[nf] = (f32x4){0.f, 0.f, 0.f, 0.f};
#pragma unroll
        for (int ks = 0; ks < 4; ++ks)
#pragma unroll
            for (int nf = 0; nf < 8; ++nf) {
                int row = nf * 16 + lrow;
                int blk = (ks * 4 + lk) ^ (row & 7);
                short8 bfr = *(const short8*)(&k_lds[row * 128 + (blk << 3)]);
                sf[nf] = MFMA16x16x32(qf[ks], bfr, sf[nf], 0, 0, 0);
            }

        // ---- scale + causal mask ----
        const bool needmask = (kv0 + 127 > qrow0 + wid * 16);
#pragma unroll
        for (int nf = 0; nf < 8; ++nf)
#pragma unroll
            for (int jj = 0; jj < 4; ++jj) {
                float s = sf[nf][jj] * 0.03125f;   // C^-0.5 = 1/32
                if (needmask &&
                    (kv0 + nf * 16 + lrow > qrow0 + wid * 16 + lk * 4 + jj)) s = -1e30f;
                sf[nf][jj] = s;
            }
        // ---- online softmax (16-lane groups), defer-max THR=8 ----
        float mt[4];
#pragma unroll
        for (int jj = 0; jj < 4; ++jj) {
            float m01 = fmaxf(sf[0][jj], sf[1][jj]);
            float m23 = fmaxf(sf[2][jj], sf[3][jj]);
            float m45 = fmaxf(sf[4][jj], sf[5][jj]);
            float m67 = fmaxf(sf[6][jj], sf[7][jj]);
            mt[jj] = fmaxf(fmaxf(m01, m23), fmaxf(m45, m67));
        }
#pragma unroll
        for (int off = 1; off < 16; off <<= 1)
#pragma unroll
            for (int jj = 0; jj < 4; ++jj)
                mt[jj] = fmaxf(mt[jj], __shfl_xor(mt[jj], off));
        bool small = true;
#pragma unroll
        for (int jj = 0; jj < 4; ++jj) small = small && (mt[jj] <= mrun[jj] + 8.f);
        if (!__all(small)) {
#pragma unroll
            for (int jj = 0; jj < 4; ++jj) {
                float mnew = fmaxf(mrun[jj], mt[jj]);
                float sc   = __expf(mrun[jj] - mnew);
                mrun[jj]   = mnew;
                lsum[jj]  *= sc;
#pragma unroll
                for (int df = 0; df < 8; ++df) of[df][jj] *= sc;
            }
        }
        float rs[4] = {0.f, 0.f, 0.f, 0.f};
#pragma unroll
        for (int nf = 0; nf < 8; ++nf)
#pragma unroll
            for (int jj = 0; jj < 4; ++jj) {
                float e = __expf(sf[nf][jj] - mrun[jj]);
                sf[nf][jj] = e;
                rs[jj] += e;
            }
#pragma unroll
        for (int off = 1; off < 16; off <<= 1)
#pragma unroll
            for (int jj = 0; jj < 4; ++jj)
                rs[jj] += __shfl_xor(rs[jj], off);
#pragma unroll
        for (int jj = 0; jj < 4; ++jj) lsum[jj] += rs[jj];

        // ---- P -> per-wave LDS (bf16, swizzled), then 4 A-frags ----
#pragma unroll
        for (int nf = 0; nf < 8; ++nf)
#pragma unroll
            for (int jj = 0; jj < 4; ++jj) {
                int row = lk * 4 + jj;
                int col = nf * 16 + lrow;
                pw[row * 128 + (((col >> 3) ^ (row & 7)) << 3) + (col & 7)] = f2bf(sf[nf][jj]);
            }
        asm volatile("s_waitcnt lgkmcnt(0)" ::: "memory");
        __builtin_amdgcn_sched_barrier(0);
        short8 paf[4];
#pragma unroll
        for (int ks2 = 0; ks2 < 4; ++ks2) {
            int blk = (ks2 * 4 + lk) ^ (lrow & 7);
            paf[ks2] = *(const short8*)(&pw[lrow * 128 + (blk << 3)]);
        }
        // ---- PV from v_lds ----
#pragma unroll
        for (int ks2 = 0; ks2 < 4; ++ks2)
#pragma unroll
            for (int df = 0; df < 8; ++df) {
                int row = df * 16 + lrow;
                int blk = (ks2 * 4 + lk) ^ (row & 7);
                short8 vf = *(const short8*)(&v_lds[row * 128 + (blk << 3)]);
                of[df] = MFMA16x16x32(paf[ks2], vf, of[df], 0, 0, 0);
            }
    }

    u16* poslab = po + (size_t)bx * (64 * 128);
#pragma unroll
    for (int df = 0; df < 8; ++df)
#pragma unroll
        for (int jj = 0; jj < 4; ++jj)
            poslab[(size_t)(wid * 16 + lk * 4 + jj) * 128 + df * 16 + lrow] = f2bf(of[df][jj]);
    if (lrow == 0) {
#pragma unroll
        for (int jj = 0; jj < 4; ++jj) {
            pm[(size_t)bx * 64 + wid * 16 + lk * 4 + jj] = mrun[jj];
            pl[(size_t)bx * 64 + wid * 16 + lk * 4 + jj] = lsum[jj];
        }
    }
}

// ---------------------------------------------------------------------------
// Kernel 3 (v5): combine z-partials (17-tile pairing); po is bf16.
// ---------------------------------------------------------------------------
__global__ __launch_bounds__(256) void k_combine(
    const u16* __restrict__ po, const float* __restrict__ pm, const float* __restrict__ pl,
    float* __restrict__ out)
{
    const int row  = blockIdx.x * 4 + (threadIdx.x >> 6);
    const int lane = threadIdx.x & 63;
    const int b  = row >> 11;
    const int t  = row & 2047;
    const int qt = t >> 6;
    const int r  = t & 63;

    const int p  = (qt < 16) ? qt : 31 - qt;
    const int za = z_small128(p);
    const int zlo = (qt < 16) ? 0 : za;
    const int zhi = (qt < 16) ? za : 8;

    float M = -1e30f;
    for (int z = zlo; z < zhi; ++z)
        M = fmaxf(M, pm[(size_t)(b + 8 * p + 128 * z) * 64 + r]);
    float den = 0.f, a0 = 0.f, a1 = 0.f;
    for (int z = zlo; z < zhi; ++z) {
        const int bxp = b + 8 * p + 128 * z;
        const float w = __expf(pm[(size_t)bxp * 64 + r] - M);
        den += w * pl[(size_t)bxp * 64 + r];
        const u16* slab = po + ((size_t)bxp * 64 + r) * 128;
        a0 += w * bf2f(slab[lane]);
        a1 += w * bf2f(slab[lane + 64]);
    }
    const float inv = 1.f / den;
    out[(size_t)row * 128 + lane]      = a0 * inv;
    out[(size_t)row * 128 + lane + 64] = a1 * inv;
}

// ---------------------------------------------------------------------------
extern "C" void kernel_launch(void* const* d_in, const int* in_sizes, int n_in,
                              void* d_out, int out_size, void* d_ws, size_t ws_size,
                              hipStream_t stream) {
    const float* x  = (const float*)d_in[0];
    const float* Wq = (const float*)d_in[1];
    const float* Wk = (const float*)d_in[2];
    const float* Wv = (const float*)d_in[3];
    float* out = (float*)d_out;

    char* ws = (char*)d_ws;
    u16*   qb  = (u16*)(ws);                         //  4 MB  [16384][128] bf16
    u16*   kb  = (u16*)(ws + (size_t)4  * 1048576);  //  4 MB  [16384][128] bf16
    u16*   vT  = (u16*)(ws + (size_t)8  * 1048576);  //  4 MB  [8][128][2048] bf16
    u16*   WTf = (u16*)(ws + (size_t)12 * 1048576);  //  0.75 MB fragment-ordered
    u16*   po  = (u16*)(ws + (size_t)13 * 1048576);  // 16.8 MB [1024][64][128] bf16
    float* pm  = (float*)(ws + (size_t)47 * 1048576);//  0.25 MB [1024][64]
    float* pl  = (float*)(ws + (size_t)48 * 1048576);//  0.25 MB [1024][64]

    k_transpose_wf<<<192, 256, 0, stream>>>(Wq, Wk, Wv, WTf);
    k_qkv_gemm8<<<256, 512, 0, stream>>>(x, WTf, qb, kb, vT);
    k_flash9<<<1024, 256, 0, stream>>>(qb, kb, vT, po, pm, pl);
    k_combine<<<4096, 256, 0, stream>>>(po, pm, pl, out);
}